// Round 1
// baseline (1010.603 us; speedup 1.0000x reference)
//
#include <hip/hip_runtime.h>

#define EDGES 1000000
#define NNODES 50000
#define NG 512

typedef __attribute__((ext_vector_type(8))) short bf16x8;
typedef __attribute__((ext_vector_type(4))) float f32x4;

__device__ __forceinline__ unsigned short f2bf(float f){
  unsigned u = __float_as_uint(f);
  u += 0x7fffu + ((u >> 16) & 1u);
  return (unsigned short)(u >> 16);
}
__device__ __forceinline__ float bf2f(unsigned short h){
  return __uint_as_float(((unsigned)h) << 16);
}

// ---------------- prep ----------------
__global__ void prep_emb(const float* __restrict__ emb, unsigned short* __restrict__ emb_bf){
  int i = blockIdx.x * 256 + threadIdx.x;
  if (i < NNODES * 64) emb_bf[i] = f2bf(emb[i]);
}

__global__ void prep_w(const float* __restrict__ W1, const float* __restrict__ W2,
                       unsigned short* __restrict__ w1t, unsigned short* __restrict__ w2t){
  int i = blockIdx.x * 256 + threadIdx.x;
  if (i < 32768){                       // W1T [256][128]
    int c = i >> 7, k = i & 127;
    w1t[i] = f2bf(W1[k * 256 + c]);
  } else {
    int j = i - 32768;
    if (j < 16384){                     // W2T [64][256]
      int n = j >> 8, k = j & 255;
      w2t[j] = f2bf(W2[k * 64 + n]);
    }
  }
}

// ---------------- counting sort by seg ----------------
__global__ void seg_hist(const int* __restrict__ ei, const int* __restrict__ batch,
                         int* __restrict__ seg, unsigned* __restrict__ hist){
  __shared__ unsigned h[NG];
  int t = threadIdx.x;
  h[t] = 0; h[t + 256] = 0;
  __syncthreads();
  for (int i = 0; i < 4; i++){
    int e = blockIdx.x * 1024 + i * 256 + t;
    if (e < EDGES){
      int s = batch[ei[e]];
      seg[e] = s;
      atomicAdd(&h[s], 1u);
    }
  }
  __syncthreads();
  atomicAdd(&hist[t], h[t]);
  atomicAdd(&hist[t + 256], h[t + 256]);
}

__global__ void scan_hist(const unsigned* __restrict__ hist, unsigned* __restrict__ cursors,
                          float* __restrict__ cnt1f){
  __shared__ unsigned s[NG];
  int t = threadIdx.x;           // 512 threads
  unsigned c = hist[t];
  s[t] = c;
  __syncthreads();
  for (int off = 1; off < NG; off <<= 1){
    unsigned v = (t >= off) ? s[t - off] : 0u;
    __syncthreads();
    s[t] += v;
    __syncthreads();
  }
  cursors[t * 16] = s[t] - c;    // exclusive prefix; padded stride (64B) to spread atomics
  cnt1f[t] = (float)(c > 0u ? c : 1u);
}

__global__ void scatter(const int* __restrict__ ei, const int* __restrict__ seg,
                        unsigned* __restrict__ cursors, int* __restrict__ sorted_e,
                        int* __restrict__ seg_s, int2* __restrict__ cr){
  for (int i = 0; i < 4; i++){
    int e = blockIdx.x * 1024 + i * 256 + threadIdx.x;
    if (e < EDGES){
      int s = seg[e];
      int pos = (int)atomicAdd(&cursors[s * 16], 1u);
      sorted_e[pos] = e;
      seg_s[pos] = s;
      cr[pos] = make_int2(ei[e], ei[EDGES + e]);
    }
  }
}

// ---------------- K1: GEMM1 + stats1 ----------------
__global__ __launch_bounds__(256) void k1_stats(
    const unsigned short* __restrict__ emb_bf, const unsigned short* __restrict__ w1t,
    const float* __restrict__ b1, const int2* __restrict__ cr, const int* __restrict__ seg_s,
    float* __restrict__ sum1, float* __restrict__ sqs1)
{
  __shared__ unsigned short A[64 * 136];   // 64 edges x 128 k, +8 pad
  __shared__ int segl[64];
  __shared__ int rseg[64];
  __shared__ int rlo[65];
  __shared__ int nrun;
  int t = threadIdx.x;
  int p0 = blockIdx.x * 64;
  {
    int el = t >> 2, part = t & 3;
    int2 e2 = cr[p0 + el];
    int node = (part < 2) ? e2.x : e2.y;
    const int4* src = (const int4*)(emb_bf + node * 64 + (part & 1) * 32);
    int4* dst = (int4*)(A + el * 136 + part * 32);
    dst[0] = src[0]; dst[1] = src[1]; dst[2] = src[2]; dst[3] = src[3];
  }
  if (t < 64) segl[t] = seg_s[p0 + t];
  __syncthreads();
  if (t == 0){
    int n = 0, cur = segl[0];
    rseg[0] = cur; rlo[0] = 0;
    for (int i = 1; i < 64; i++)
      if (segl[i] != cur){ cur = segl[i]; n++; rseg[n] = cur; rlo[n] = i; }
    rlo[n + 1] = 64; nrun = n + 1;
  }
  __syncthreads();

  int w = t >> 6, lane = t & 63, q = lane >> 4, c = lane & 15;
  int nb = w * 64;
  f32x4 acc[4][4];
  for (int a = 0; a < 4; a++) for (int b = 0; b < 4; b++) for (int r = 0; r < 4; r++) acc[a][b][r] = 0.f;

  for (int k0 = 0; k0 < 128; k0 += 32){
    bf16x8 af[4], bw[4];
    for (int tt = 0; tt < 4; tt++) af[tt] = *(const bf16x8*)(A + (tt * 16 + c) * 136 + k0 + q * 8);
    for (int n4 = 0; n4 < 4; n4++) bw[n4] = *(const bf16x8*)(w1t + (nb + n4 * 16 + c) * 128 + k0 + q * 8);
    for (int tt = 0; tt < 4; tt++)
      for (int n4 = 0; n4 < 4; n4++)
        acc[tt][n4] = __builtin_amdgcn_mfma_f32_16x16x32_bf16(af[tt], bw[n4], acc[tt][n4], 0, 0, 0);
  }

  float b1v[4];
  for (int n4 = 0; n4 < 4; n4++) b1v[n4] = b1[nb + n4 * 16 + c];
  int nr = nrun;
  for (int rr = 0; rr < nr; rr++){
    int s = rseg[rr], lo = rlo[rr], hi = rlo[rr + 1];
    for (int n4 = 0; n4 < 4; n4++){
      float sm = 0.f, sq = 0.f;
      for (int tt = 0; tt < 4; tt++){
        int elb = tt * 16 + q * 4;
        for (int r = 0; r < 4; r++){
          int el = elb + r;
          if (el >= lo && el < hi){
            float v = acc[tt][n4][r] + b1v[n4];
            sm += v; sq += v * v;
          }
        }
      }
      sm += __shfl_xor(sm, 16); sq += __shfl_xor(sq, 16);
      sm += __shfl_xor(sm, 32); sq += __shfl_xor(sq, 32);
      if (q == 0){
        int ch = nb + n4 * 16 + c;
        atomicAdd(&sum1[s * 256 + ch], sm);
        atomicAdd(&sqs1[s * 256 + ch], sq);
      }
    }
  }
}

// ---------------- finalize ----------------
__global__ void finalize1(const float* __restrict__ sum1, const float* __restrict__ sqs1,
                          const float* __restrict__ cnt1f, float* __restrict__ mean1,
                          float* __restrict__ rstd1){
  int i = blockIdx.x * 256 + threadIdx.x;   // 512*256
  int g = i >> 8;
  float cnt = cnt1f[g];
  float m = sum1[i] / cnt;
  float v = sqs1[i] / cnt - m * m;
  v = fmaxf(v, 0.f);
  mean1[i] = m;
  rstd1[i] = rsqrtf(v + 1e-5f);
}

__global__ void finalize2(const float* __restrict__ sum2, const float* __restrict__ sqs2,
                          const float* __restrict__ cnt1f, float* __restrict__ mean2,
                          float* __restrict__ rstd2){
  int i = blockIdx.x * 256 + threadIdx.x;   // 512*64
  int g = i >> 6;
  float cnt = cnt1f[g];
  float m = sum2[i] / cnt;
  float v = sqs2[i] / cnt - m * m;
  v = fmaxf(v, 0.f);
  mean2[i] = m;
  rstd2[i] = rsqrtf(v + 1e-5f);
}

// ---------------- K2: GEMM1 -> norm/relu -> GEMM2 + stats2 + x2 store ----------------
__global__ __launch_bounds__(256) void k2_main(
    const unsigned short* __restrict__ emb_bf, const unsigned short* __restrict__ w1t,
    const unsigned short* __restrict__ w2t,
    const float* __restrict__ b1, const float* __restrict__ b2,
    const int2* __restrict__ cr, const int* __restrict__ seg_s,
    const float* __restrict__ mean1, const float* __restrict__ rstd1,
    float* __restrict__ sum2, float* __restrict__ sqs2,
    unsigned short* __restrict__ x2)
{
  __shared__ unsigned short A[64 * 136];
  __shared__ unsigned short Y[64 * 264];   // y1 = relu(norm(x1)), [edge][256ch] +8 pad
  __shared__ int segl[64];
  __shared__ int rseg[64];
  __shared__ int rlo[65];
  __shared__ int nrun;
  int t = threadIdx.x;
  int p0 = blockIdx.x * 64;
  {
    int el = t >> 2, part = t & 3;
    int2 e2 = cr[p0 + el];
    int node = (part < 2) ? e2.x : e2.y;
    const int4* src = (const int4*)(emb_bf + node * 64 + (part & 1) * 32);
    int4* dst = (int4*)(A + el * 136 + part * 32);
    dst[0] = src[0]; dst[1] = src[1]; dst[2] = src[2]; dst[3] = src[3];
  }
  if (t < 64) segl[t] = seg_s[p0 + t];
  __syncthreads();
  if (t == 0){
    int n = 0, cur = segl[0];
    rseg[0] = cur; rlo[0] = 0;
    for (int i = 1; i < 64; i++)
      if (segl[i] != cur){ cur = segl[i]; n++; rseg[n] = cur; rlo[n] = i; }
    rlo[n + 1] = 64; nrun = n + 1;
  }
  __syncthreads();

  int w = t >> 6, lane = t & 63, q = lane >> 4, c = lane & 15;
  int nb = w * 64;
  f32x4 acc[4][4];
  for (int a = 0; a < 4; a++) for (int b = 0; b < 4; b++) for (int r = 0; r < 4; r++) acc[a][b][r] = 0.f;

  for (int k0 = 0; k0 < 128; k0 += 32){
    bf16x8 af[4], bw[4];
    for (int tt = 0; tt < 4; tt++) af[tt] = *(const bf16x8*)(A + (tt * 16 + c) * 136 + k0 + q * 8);
    for (int n4 = 0; n4 < 4; n4++) bw[n4] = *(const bf16x8*)(w1t + (nb + n4 * 16 + c) * 128 + k0 + q * 8);
    for (int tt = 0; tt < 4; tt++)
      for (int n4 = 0; n4 < 4; n4++)
        acc[tt][n4] = __builtin_amdgcn_mfma_f32_16x16x32_bf16(af[tt], bw[n4], acc[tt][n4], 0, 0, 0);
  }

  float b1v[4];
  for (int n4 = 0; n4 < 4; n4++) b1v[n4] = b1[nb + n4 * 16 + c];
  int nr = nrun;
  for (int rr = 0; rr < nr; rr++){
    int s = rseg[rr], lo = rlo[rr], hi = rlo[rr + 1];
    for (int n4 = 0; n4 < 4; n4++){
      int ch = nb + n4 * 16 + c;
      float m1 = mean1[s * 256 + ch];
      float r1 = rstd1[s * 256 + ch];
      for (int tt = 0; tt < 4; tt++){
        int elb = tt * 16 + q * 4;
        for (int r = 0; r < 4; r++){
          int el = elb + r;
          if (el >= lo && el < hi){
            float v = acc[tt][n4][r] + b1v[n4];
            float y = fmaxf(0.f, (v - m1) * r1);
            Y[el * 264 + ch] = f2bf(y);
          }
        }
      }
    }
  }
  __syncthreads();

  // GEMM2: wave w owns out-channels [w*16, w*16+16)
  f32x4 acc2[4];
  for (int tt = 0; tt < 4; tt++) for (int r = 0; r < 4; r++) acc2[tt][r] = 0.f;
  int ch2 = w * 16 + c;
  for (int kc = 0; kc < 8; kc++){
    int k0 = kc * 32;
    bf16x8 bfr = *(const bf16x8*)(w2t + ch2 * 256 + k0 + q * 8);
    for (int tt = 0; tt < 4; tt++){
      bf16x8 afr = *(const bf16x8*)(Y + (tt * 16 + c) * 264 + k0 + q * 8);
      acc2[tt] = __builtin_amdgcn_mfma_f32_16x16x32_bf16(afr, bfr, acc2[tt], 0, 0, 0);
    }
  }

  float b2v = b2[ch2];
  for (int rr = 0; rr < nr; rr++){
    int s = rseg[rr], lo = rlo[rr], hi = rlo[rr + 1];
    float sm = 0.f, sq = 0.f;
    for (int tt = 0; tt < 4; tt++){
      int elb = tt * 16 + q * 4;
      for (int r = 0; r < 4; r++){
        int el = elb + r;
        if (el >= lo && el < hi){
          float v = acc2[tt][r] + b2v;
          sm += v; sq += v * v;
        }
      }
    }
    sm += __shfl_xor(sm, 16); sq += __shfl_xor(sq, 16);
    sm += __shfl_xor(sm, 32); sq += __shfl_xor(sq, 32);
    if (q == 0){
      atomicAdd(&sum2[s * 64 + ch2], sm);
      atomicAdd(&sqs2[s * 64 + ch2], sq);
    }
  }
  for (int tt = 0; tt < 4; tt++){
    for (int r = 0; r < 4; r++){
      int el = tt * 16 + q * 4 + r;
      float v = acc2[tt][r] + b2v;
      x2[(size_t)(p0 + el) * 64 + ch2] = f2bf(v);
    }
  }
}

// ---------------- K3: normalize2 + GEMV W3 ----------------
__global__ __launch_bounds__(256) void k3_out(
    const unsigned short* __restrict__ x2, const int* __restrict__ seg_s,
    const int* __restrict__ sorted_e, const float* __restrict__ mean2,
    const float* __restrict__ rstd2, const float* __restrict__ W3,
    const float* __restrict__ b3, float* __restrict__ out)
{
  int lane = threadIdx.x & 63;
  int wid = (blockIdx.x * 256 + threadIdx.x) >> 6;
  int nw = gridDim.x * 4;
  float w3v = W3[lane];
  float b3v = b3[0];
  for (int pp = wid; pp < EDGES; pp += nw){
    int s = seg_s[pp];
    float v = bf2f(x2[(size_t)pp * 64 + lane]);
    int ci = s * 64 + lane;
    float y = fmaxf(0.f, (v - mean2[ci]) * rstd2[ci]);
    float tv = y * w3v;
    tv += __shfl_xor(tv, 32);
    tv += __shfl_xor(tv, 16);
    tv += __shfl_xor(tv, 8);
    tv += __shfl_xor(tv, 4);
    tv += __shfl_xor(tv, 2);
    tv += __shfl_xor(tv, 1);
    if (lane == 0) out[sorted_e[pp]] = tv + b3v;
  }
}

// ---------------- launch ----------------
extern "C" void kernel_launch(void* const* d_in, const int* in_sizes, int n_in,
                              void* d_out, int out_size, void* d_ws, size_t ws_size,
                              hipStream_t stream)
{
  (void)in_sizes; (void)n_in; (void)out_size;
  const float* emb = (const float*)d_in[0];
  const float* W1  = (const float*)d_in[1];
  const float* b1  = (const float*)d_in[2];
  const float* W2  = (const float*)d_in[3];
  const float* b2  = (const float*)d_in[4];
  const float* W3  = (const float*)d_in[5];
  const float* b3  = (const float*)d_in[6];
  const int* ei    = (const int*)d_in[7];
  const int* batch = (const int*)d_in[8];
  float* out = (float*)d_out;

  char* p = (char*)d_ws;
  size_t off = 0;
  auto take = [&](size_t n) -> char* {
    char* r = p + off;
    off += (n + 255) & ~(size_t)255;
    return r;
  };

  unsigned short* emb_bf = (unsigned short*)take((size_t)NNODES * 64 * 2);
  unsigned short* w1t    = (unsigned short*)take(32768 * 2);
  unsigned short* w2t    = (unsigned short*)take(16384 * 2);
  int*  seg       = (int*)take((size_t)EDGES * 4);
  int*  sorted_e  = (int*)take((size_t)EDGES * 4);
  int*  seg_s     = (int*)take((size_t)EDGES * 4);
  int2* cr        = (int2*)take((size_t)EDGES * 8);
  unsigned short* x2 = (unsigned short*)take((size_t)EDGES * 64 * 2);
  float* mean1 = (float*)take(512 * 256 * 4);
  float* rstd1 = (float*)take(512 * 256 * 4);
  float* mean2 = (float*)take(512 * 64 * 4);
  float* rstd2 = (float*)take(512 * 64 * 4);
  float* cnt1f = (float*)take(512 * 4);
  // zero-init region (contiguous)
  char* zbase = p + off;
  unsigned* hist    = (unsigned*)take(512 * 4);
  unsigned* cursors = (unsigned*)take(512 * 16 * 4);
  float* sum1 = (float*)take(512 * 256 * 4);
  float* sqs1 = (float*)take(512 * 256 * 4);
  float* sum2 = (float*)take(512 * 64 * 4);
  float* sqs2 = (float*)take(512 * 64 * 4);
  size_t zsize = (size_t)((p + off) - zbase);

  if (ws_size < off) return;  // workspace too small — fail loudly via poison

  hipMemsetAsync(zbase, 0, zsize, stream);
  prep_emb<<<(NNODES * 64) / 256, 256, 0, stream>>>(emb, emb_bf);
  prep_w<<<192, 256, 0, stream>>>(W1, W2, w1t, w2t);
  seg_hist<<<977, 256, 0, stream>>>(ei, batch, seg, hist);
  scan_hist<<<1, 512, 0, stream>>>(hist, cursors, cnt1f);
  scatter<<<977, 256, 0, stream>>>(ei, seg, cursors, sorted_e, seg_s, cr);
  k1_stats<<<EDGES / 64, 256, 0, stream>>>(emb_bf, w1t, b1, cr, seg_s, sum1, sqs1);
  finalize1<<<512, 256, 0, stream>>>(sum1, sqs1, cnt1f, mean1, rstd1);
  k2_main<<<EDGES / 64, 256, 0, stream>>>(emb_bf, w1t, w2t, b1, b2, cr, seg_s,
                                          mean1, rstd1, sum2, sqs2, x2);
  finalize2<<<128, 256, 0, stream>>>(sum2, sqs2, cnt1f, mean2, rstd2);
  k3_out<<<2048, 256, 0, stream>>>(x2, seg_s, sorted_e, mean2, rstd2, W3, b3, out);
}

// Round 2
// 803.730 us; speedup vs baseline: 1.2574x; 1.2574x over previous
//
#include <hip/hip_runtime.h>

#define EDGES 1000000
#define NNODES 50000
#define NG 512
#define NTILES 15625  // EDGES/64

typedef __attribute__((ext_vector_type(8))) short bf16x8;
typedef __attribute__((ext_vector_type(4))) float f32x4;

__device__ __forceinline__ unsigned short f2bf(float f){
  unsigned u = __float_as_uint(f);
  u += 0x7fffu + ((u >> 16) & 1u);
  return (unsigned short)(u >> 16);
}
__device__ __forceinline__ float bf2f(unsigned short h){
  return __uint_as_float(((unsigned)h) << 16);
}

// ---------------- prep ----------------
__global__ void prep_emb(const float* __restrict__ emb, unsigned short* __restrict__ emb_bf){
  int i = blockIdx.x * 256 + threadIdx.x;
  if (i < NNODES * 64) emb_bf[i] = f2bf(emb[i]);
}

// w1tn[j][k] = (j<256 ? W1[k][j] : W1[k+64][j-256]), j in [0,512), k in [0,64)
// w2t[n][k]  = W2[k][n], n in [0,64), k in [0,256)
__global__ void prep_w(const float* __restrict__ W1, const float* __restrict__ W2,
                       unsigned short* __restrict__ w1tn, unsigned short* __restrict__ w2t){
  int i = blockIdx.x * 256 + threadIdx.x;
  if (i < 32768){
    int j = i >> 6, k = i & 63;
    float v = (j < 256) ? W1[k * 256 + j] : W1[(k + 64) * 256 + (j - 256)];
    w1tn[i] = f2bf(v);
  } else {
    int jj = i - 32768;
    if (jj < 16384){
      int n = jj >> 8, k = jj & 255;
      w2t[jj] = f2bf(W2[k * 64 + n]);
    }
  }
}

// ---------------- counting sort by seg ----------------
__global__ void seg_hist(const int* __restrict__ ei, const int* __restrict__ batch,
                         unsigned* __restrict__ hist){
  __shared__ unsigned h[NG];
  int t = threadIdx.x;
  h[t] = 0; h[t + 256] = 0;
  __syncthreads();
  for (int i = 0; i < 4; i++){
    int e = blockIdx.x * 1024 + i * 256 + t;
    if (e < EDGES){
      int s = batch[ei[e]];
      atomicAdd(&h[s], 1u);
    }
  }
  __syncthreads();
  atomicAdd(&hist[t], h[t]);
  atomicAdd(&hist[t + 256], h[t + 256]);
}

__global__ void scan_hist(const unsigned* __restrict__ hist, unsigned* __restrict__ cursors,
                          float* __restrict__ cnt1f){
  __shared__ unsigned s[NG];
  int t = threadIdx.x;           // 512 threads
  unsigned c = hist[t];
  s[t] = c;
  __syncthreads();
  for (int off = 1; off < NG; off <<= 1){
    unsigned v = (t >= off) ? s[t - off] : 0u;
    __syncthreads();
    s[t] += v;
    __syncthreads();
  }
  cursors[t * 16] = s[t] - c;    // exclusive prefix; padded stride to spread atomics
  cnt1f[t] = (float)(c > 0u ? c : 1u);
}

__global__ void scatter(const int* __restrict__ ei, const int* __restrict__ batch,
                        unsigned* __restrict__ cursors, int* __restrict__ sorted_e,
                        int* __restrict__ seg_s, int2* __restrict__ cr){
  for (int i = 0; i < 4; i++){
    int e = blockIdx.x * 1024 + i * 256 + threadIdx.x;
    if (e < EDGES){
      int cnode = ei[e];
      int s = batch[cnode];
      int pos = (int)atomicAdd(&cursors[s * 16], 1u);
      sorted_e[pos] = e;
      seg_s[pos] = s;
      cr[pos] = make_int2(cnode, ei[EDGES + e]);
    }
  }
}

// ---------------- node GEMM: P[node][512] = emb @ [W1top | W1bot] ----------------
__global__ __launch_bounds__(256) void node_gemm(
    const unsigned short* __restrict__ emb_bf, const unsigned short* __restrict__ w1tn,
    unsigned short* __restrict__ P)
{
  __shared__ unsigned short As[64 * 72];   // 64 nodes x 64 k, +8 pad
  int t = threadIdx.x;
  int n0 = blockIdx.x * 64;
  {
    int nl = t >> 2, part = t & 3;
    int node = n0 + nl; if (node >= NNODES) node = 0;
    const int4* src = (const int4*)(emb_bf + node * 64 + part * 16);
    int4* dst = (int4*)(As + nl * 72 + part * 16);
    dst[0] = src[0]; dst[1] = src[1];
  }
  __syncthreads();
  int w = t >> 6, lane = t & 63, q = lane >> 4, c = lane & 15;
  f32x4 acc[4][8];
  for (int a = 0; a < 4; a++) for (int b = 0; b < 8; b++) for (int r = 0; r < 4; r++) acc[a][b][r] = 0.f;
  for (int k0 = 0; k0 < 64; k0 += 32){
    bf16x8 af[4];
    for (int tt = 0; tt < 4; tt++) af[tt] = *(const bf16x8*)(As + (tt * 16 + c) * 72 + k0 + q * 8);
    for (int n4 = 0; n4 < 8; n4++){
      bf16x8 bw = *(const bf16x8*)(w1tn + (w * 128 + n4 * 16 + c) * 64 + k0 + q * 8);
      for (int tt = 0; tt < 4; tt++)
        acc[tt][n4] = __builtin_amdgcn_mfma_f32_16x16x32_bf16(af[tt], bw, acc[tt][n4], 0, 0, 0);
    }
  }
  for (int tt = 0; tt < 4; tt++){
    for (int r = 0; r < 4; r++){
      int node = n0 + tt * 16 + q * 4 + r;
      if (node < NNODES){
        unsigned short* dst = P + (size_t)node * 512 + w * 128 + c;
        for (int n4 = 0; n4 < 8; n4++) dst[n4 * 16] = f2bf(acc[tt][n4][r]);
      }
    }
  }
}

// ---------------- K1: gather + segmented stats1 ----------------
__global__ __launch_bounds__(256) void k1_gather(
    const unsigned short* __restrict__ P, const int2* __restrict__ cr,
    const int* __restrict__ seg_s, float* __restrict__ sum1, float* __restrict__ sqs1)
{
  int lane = threadIdx.x & 63;
  int wid = (blockIdx.x * 256 + threadIdx.x) >> 6;
  if (wid >= NTILES) return;
  int p0 = wid * 64;
  int2 mycr = cr[p0 + lane];
  int myseg = seg_s[p0 + lane];
  int c4 = lane * 4;
  float sm0 = 0.f, sm1 = 0.f, sm2 = 0.f, sm3 = 0.f;
  float q0 = 0.f, q1 = 0.f, q2 = 0.f, q3 = 0.f;
  int cur = __shfl(myseg, 0);
  ushort4 a = *(const ushort4*)(P + (size_t)__shfl(mycr.x, 0) * 512 + c4);
  ushort4 b = *(const ushort4*)(P + (size_t)__shfl(mycr.y, 0) * 512 + 256 + c4);
  for (int e = 0; e < 64; e++){
    ushort4 an = a, bn = b;
    if (e < 63){
      an = *(const ushort4*)(P + (size_t)__shfl(mycr.x, e + 1) * 512 + c4);
      bn = *(const ushort4*)(P + (size_t)__shfl(mycr.y, e + 1) * 512 + 256 + c4);
    }
    int s = __shfl(myseg, e);
    if (s != cur){
      float* sp = sum1 + cur * 256 + c4;
      float* qp = sqs1 + cur * 256 + c4;
      atomicAdd(sp + 0, sm0); atomicAdd(sp + 1, sm1); atomicAdd(sp + 2, sm2); atomicAdd(sp + 3, sm3);
      atomicAdd(qp + 0, q0);  atomicAdd(qp + 1, q1);  atomicAdd(qp + 2, q2);  atomicAdd(qp + 3, q3);
      sm0 = sm1 = sm2 = sm3 = 0.f; q0 = q1 = q2 = q3 = 0.f;
      cur = s;
    }
    float x0 = bf2f(a.x) + bf2f(b.x);
    float x1 = bf2f(a.y) + bf2f(b.y);
    float x2v = bf2f(a.z) + bf2f(b.z);
    float x3 = bf2f(a.w) + bf2f(b.w);
    sm0 += x0; q0 += x0 * x0;
    sm1 += x1; q1 += x1 * x1;
    sm2 += x2v; q2 += x2v * x2v;
    sm3 += x3; q3 += x3 * x3;
    a = an; b = bn;
  }
  float* sp = sum1 + cur * 256 + c4;
  float* qp = sqs1 + cur * 256 + c4;
  atomicAdd(sp + 0, sm0); atomicAdd(sp + 1, sm1); atomicAdd(sp + 2, sm2); atomicAdd(sp + 3, sm3);
  atomicAdd(qp + 0, q0);  atomicAdd(qp + 1, q1);  atomicAdd(qp + 2, q2);  atomicAdd(qp + 3, q3);
}

// ---------------- finalize ----------------
__global__ void finalize1(const float* __restrict__ sum1, const float* __restrict__ sqs1,
                          const float* __restrict__ cnt1f, float* __restrict__ mean1,
                          float* __restrict__ rstd1){
  int i = blockIdx.x * 256 + threadIdx.x;   // 512*256
  int g = i >> 8;
  float cnt = cnt1f[g];
  float m = sum1[i] / cnt;
  float v = sqs1[i] / cnt - m * m;
  v = fmaxf(v, 0.f);
  mean1[i] = m;
  rstd1[i] = rsqrtf(v + 1e-5f);
}

__global__ void finalize2(const float* __restrict__ sum2, const float* __restrict__ sqs2,
                          const float* __restrict__ cnt1f, float* __restrict__ mean2,
                          float* __restrict__ rstd2){
  int i = blockIdx.x * 256 + threadIdx.x;   // 512*64
  int g = i >> 6;
  float cnt = cnt1f[g];
  float m = sum2[i] / cnt;
  float v = sqs2[i] / cnt - m * m;
  v = fmaxf(v, 0.f);
  mean2[i] = m;
  rstd2[i] = rsqrtf(v + 1e-5f);
}

// ---------------- K2: gather -> norm/relu -> GEMM2 + stats2 + x2 store ----------------
__global__ __launch_bounds__(256) void k2_fused(
    const unsigned short* __restrict__ P, const unsigned short* __restrict__ w2t,
    const int2* __restrict__ cr, const int* __restrict__ seg_s,
    const float* __restrict__ mean1, const float* __restrict__ rstd1,
    float* __restrict__ sum2, float* __restrict__ sqs2,
    unsigned short* __restrict__ x2)
{
  __shared__ unsigned short Y[64 * 264];   // y1 = relu(norm(x1)), [edge][256ch] +8 pad
  __shared__ int segl[64];
  __shared__ int rseg[64];
  __shared__ int rlo[65];
  __shared__ int nrun;
  int t = threadIdx.x;
  int p0 = blockIdx.x * 64;
  if (t < 64) segl[t] = seg_s[p0 + t];
  __syncthreads();
  if (t == 0){
    int n = 0, curq = segl[0];
    rseg[0] = curq; rlo[0] = 0;
    for (int i = 1; i < 64; i++)
      if (segl[i] != curq){ curq = segl[i]; n++; rseg[n] = curq; rlo[n] = i; }
    rlo[n + 1] = 64; nrun = n + 1;
  }
  int w = t >> 6, lane = t & 63, q = lane >> 4, c = lane & 15;
  int c4 = lane * 4;
  int elb0 = w * 16;
  int2 mycr = cr[p0 + elb0 + (lane & 15)];
  int myseg = segl[elb0 + (lane & 15)];
  for (int e = 0; e < 16; e++){
    int s  = __shfl(myseg, e);
    int ce = __shfl(mycr.x, e);
    int re = __shfl(mycr.y, e);
    ushort4 a = *(const ushort4*)(P + (size_t)ce * 512 + c4);
    ushort4 b = *(const ushort4*)(P + (size_t)re * 512 + 256 + c4);
    float4 m = *(const float4*)(mean1 + s * 256 + c4);
    float4 r = *(const float4*)(rstd1 + s * 256 + c4);
    ushort4 y;
    y.x = f2bf(fmaxf(0.f, (bf2f(a.x) + bf2f(b.x) - m.x) * r.x));
    y.y = f2bf(fmaxf(0.f, (bf2f(a.y) + bf2f(b.y) - m.y) * r.y));
    y.z = f2bf(fmaxf(0.f, (bf2f(a.z) + bf2f(b.z) - m.z) * r.z));
    y.w = f2bf(fmaxf(0.f, (bf2f(a.w) + bf2f(b.w) - m.w) * r.w));
    *(ushort4*)(Y + (elb0 + e) * 264 + c4) = y;
  }
  __syncthreads();

  // GEMM2: wave w owns out-channels [w*16, w*16+16)
  f32x4 acc2[4];
  for (int tt = 0; tt < 4; tt++) for (int r = 0; r < 4; r++) acc2[tt][r] = 0.f;
  int ch2 = w * 16 + c;
  for (int kc = 0; kc < 8; kc++){
    int k0 = kc * 32;
    bf16x8 bfr = *(const bf16x8*)(w2t + ch2 * 256 + k0 + q * 8);
    for (int tt = 0; tt < 4; tt++){
      bf16x8 afr = *(const bf16x8*)(Y + (tt * 16 + c) * 264 + k0 + q * 8);
      acc2[tt] = __builtin_amdgcn_mfma_f32_16x16x32_bf16(afr, bfr, acc2[tt], 0, 0, 0);
    }
  }

  int nr = nrun;
  for (int rr = 0; rr < nr; rr++){
    int s = rseg[rr], lo = rlo[rr], hi = rlo[rr + 1];
    float sm = 0.f, sq = 0.f;
    for (int tt = 0; tt < 4; tt++){
      int elb = tt * 16 + q * 4;
      for (int r = 0; r < 4; r++){
        int el = elb + r;
        if (el >= lo && el < hi){
          float v = acc2[tt][r];
          sm += v; sq += v * v;
        }
      }
    }
    sm += __shfl_xor(sm, 16); sq += __shfl_xor(sq, 16);
    sm += __shfl_xor(sm, 32); sq += __shfl_xor(sq, 32);
    if (q == 0){
      atomicAdd(&sum2[s * 64 + ch2], sm);
      atomicAdd(&sqs2[s * 64 + ch2], sq);
    }
  }
  for (int tt = 0; tt < 4; tt++){
    for (int r = 0; r < 4; r++){
      int el = tt * 16 + q * 4 + r;
      x2[(size_t)(p0 + el) * 64 + ch2] = f2bf(acc2[tt][r]);
    }
  }
}

// ---------------- K3: normalize2 + GEMV W3 ----------------
__global__ __launch_bounds__(256) void k3_out(
    const unsigned short* __restrict__ x2, const int* __restrict__ seg_s,
    const int* __restrict__ sorted_e, const float* __restrict__ mean2,
    const float* __restrict__ rstd2, const float* __restrict__ W3,
    const float* __restrict__ b3, float* __restrict__ out)
{
  int lane = threadIdx.x & 63;
  int wid = (blockIdx.x * 256 + threadIdx.x) >> 6;
  int nw = gridDim.x * 4;
  float w3v = W3[lane];
  float b3v = b3[0];
  for (int pp = wid; pp < EDGES; pp += nw){
    int s = seg_s[pp];
    float v = bf2f(x2[(size_t)pp * 64 + lane]);
    int ci = s * 64 + lane;
    float y = fmaxf(0.f, (v - mean2[ci]) * rstd2[ci]);
    float tv = y * w3v;
    tv += __shfl_xor(tv, 32);
    tv += __shfl_xor(tv, 16);
    tv += __shfl_xor(tv, 8);
    tv += __shfl_xor(tv, 4);
    tv += __shfl_xor(tv, 2);
    tv += __shfl_xor(tv, 1);
    if (lane == 0) out[sorted_e[pp]] = tv + b3v;
  }
}

// ---------------- launch ----------------
extern "C" void kernel_launch(void* const* d_in, const int* in_sizes, int n_in,
                              void* d_out, int out_size, void* d_ws, size_t ws_size,
                              hipStream_t stream)
{
  (void)in_sizes; (void)n_in; (void)out_size;
  const float* emb = (const float*)d_in[0];
  const float* W1  = (const float*)d_in[1];
  const float* W2  = (const float*)d_in[3];
  const float* W3  = (const float*)d_in[5];
  const float* b3  = (const float*)d_in[6];
  const int* ei    = (const int*)d_in[7];
  const int* batch = (const int*)d_in[8];
  float* out = (float*)d_out;

  char* p = (char*)d_ws;
  size_t off = 0;
  auto take = [&](size_t n) -> char* {
    char* r = p + off;
    off += (n + 255) & ~(size_t)255;
    return r;
  };

  unsigned short* emb_bf = (unsigned short*)take((size_t)NNODES * 64 * 2);
  unsigned short* w1tn   = (unsigned short*)take(32768 * 2);
  unsigned short* w2t    = (unsigned short*)take(16384 * 2);
  int*  sorted_e  = (int*)take((size_t)EDGES * 4);
  int*  seg_s     = (int*)take((size_t)EDGES * 4);
  int2* cr        = (int2*)take((size_t)EDGES * 8);
  unsigned short* P  = (unsigned short*)take((size_t)NNODES * 512 * 2);
  unsigned short* x2 = (unsigned short*)take((size_t)EDGES * 64 * 2);
  float* mean1 = (float*)take(512 * 256 * 4);
  float* rstd1 = (float*)take(512 * 256 * 4);
  float* mean2 = (float*)take(512 * 64 * 4);
  float* rstd2 = (float*)take(512 * 64 * 4);
  float* cnt1f = (float*)take(512 * 4);
  // zero-init region (contiguous)
  char* zbase = p + off;
  unsigned* hist    = (unsigned*)take(512 * 4);
  unsigned* cursors = (unsigned*)take(512 * 16 * 4);
  float* sum1 = (float*)take(512 * 256 * 4);
  float* sqs1 = (float*)take(512 * 256 * 4);
  float* sum2 = (float*)take(512 * 64 * 4);
  float* sqs2 = (float*)take(512 * 64 * 4);
  size_t zsize = (size_t)((p + off) - zbase);

  if (ws_size < off) return;  // workspace too small — fail loudly via poison

  hipMemsetAsync(zbase, 0, zsize, stream);
  prep_emb<<<(NNODES * 64) / 256, 256, 0, stream>>>(emb, emb_bf);
  prep_w<<<192, 256, 0, stream>>>(W1, W2, w1tn, w2t);
  seg_hist<<<977, 256, 0, stream>>>(ei, batch, hist);
  scan_hist<<<1, 512, 0, stream>>>(hist, cursors, cnt1f);
  scatter<<<977, 256, 0, stream>>>(ei, batch, cursors, sorted_e, seg_s, cr);
  node_gemm<<<(NNODES + 63) / 64, 256, 0, stream>>>(emb_bf, w1tn, P);
  k1_gather<<<(NTILES + 3) / 4, 256, 0, stream>>>(P, cr, seg_s, sum1, sqs1);
  finalize1<<<512, 256, 0, stream>>>(sum1, sqs1, cnt1f, mean1, rstd1);
  k2_fused<<<NTILES, 256, 0, stream>>>(P, w2t, cr, seg_s, mean1, rstd1, sum2, sqs2, x2);
  finalize2<<<128, 256, 0, stream>>>(sum2, sqs2, cnt1f, mean2, rstd2);
  k3_out<<<2048, 256, 0, stream>>>(x2, seg_s, sorted_e, mean2, rstd2, W3, b3, out);
}

// Round 3
// 663.508 us; speedup vs baseline: 1.5231x; 1.2113x over previous
//
#include <hip/hip_runtime.h>
#include <hip/hip_bf16.h>

#define EDGES 1000000
#define NNODES 50000
#define NG 512
#define NTILES 15625  // EDGES/64

typedef __attribute__((ext_vector_type(8))) short bf16x8;
typedef __attribute__((ext_vector_type(4))) float f32x4;

__device__ __forceinline__ unsigned short f2bf(float f){
  unsigned u = __float_as_uint(f);
  u += 0x7fffu + ((u >> 16) & 1u);
  return (unsigned short)(u >> 16);
}
__device__ __forceinline__ float bf2f(unsigned short h){
  return __uint_as_float(((unsigned)h) << 16);
}
__device__ __forceinline__ unsigned pk2bf(float x, float y){
  __hip_bfloat162 h = __float22bfloat162_rn(make_float2(x, y));
  union { __hip_bfloat162 h; unsigned u; } cv; cv.h = h;
  return cv.u;
}

// ---------------- prep: emb->bf16, W1->w1tn, W2->w2t ----------------
// w1tn[j][k] = (j<256 ? W1[k][j] : W1[k+64][j-256]), j in [0,512), k in [0,64)
// w2t[n][k]  = W2[k][n], n in [0,64), k in [0,256)
__global__ void prep_all(const float* __restrict__ emb, const float* __restrict__ W1,
                         const float* __restrict__ W2,
                         unsigned short* __restrict__ emb_bf,
                         unsigned short* __restrict__ w1tn, unsigned short* __restrict__ w2t){
  int i = blockIdx.x * 256 + threadIdx.x;
  if (i < NNODES * 64){
    emb_bf[i] = f2bf(emb[i]);
  } else {
    int j = i - NNODES * 64;
    if (j < 32768){
      int jj = j >> 6, k = j & 63;
      float v = (jj < 256) ? W1[k * 256 + jj] : W1[(k + 64) * 256 + (jj - 256)];
      w1tn[j] = f2bf(v);
    } else {
      int jj = j - 32768;
      if (jj < 16384){
        int n = jj >> 8, k = jj & 255;
        w2t[jj] = f2bf(W2[k * 64 + n]);
      }
    }
  }
}

// ---------------- counting sort by seg ----------------
__global__ void seg_hist(const int* __restrict__ ei, const int* __restrict__ batch,
                         unsigned* __restrict__ hist){
  __shared__ unsigned h[NG];
  int t = threadIdx.x;
  h[t] = 0; h[t + 256] = 0;
  __syncthreads();
  for (int i = 0; i < 4; i++){
    int e = blockIdx.x * 1024 + i * 256 + t;
    if (e < EDGES){
      int s = batch[ei[e]];
      atomicAdd(&h[s], 1u);
    }
  }
  __syncthreads();
  atomicAdd(&hist[t], h[t]);
  atomicAdd(&hist[t + 256], h[t + 256]);
}

__global__ void scan_hist(const unsigned* __restrict__ hist, unsigned* __restrict__ cursors,
                          float* __restrict__ cnt1f){
  __shared__ unsigned s[NG];
  int t = threadIdx.x;           // 512 threads
  unsigned c = hist[t];
  s[t] = c;
  __syncthreads();
  for (int off = 1; off < NG; off <<= 1){
    unsigned v = (t >= off) ? s[t - off] : 0u;
    __syncthreads();
    s[t] += v;
    __syncthreads();
  }
  cursors[t * 16] = s[t] - c;    // exclusive prefix; padded stride to spread atomics
  cnt1f[t] = (float)(c > 0u ? c : 1u);
}

// emeta[pos] = (col, row, seg, orig_edge)
__global__ void scatter(const int* __restrict__ ei, const int* __restrict__ batch,
                        unsigned* __restrict__ cursors, int4* __restrict__ emeta){
  for (int i = 0; i < 4; i++){
    int e = blockIdx.x * 1024 + i * 256 + threadIdx.x;
    if (e < EDGES){
      int cn = ei[e];
      int s = batch[cn];
      int pos = (int)atomicAdd(&cursors[s * 16], 1u);
      emeta[pos] = make_int4(cn, ei[EDGES + e], s, e);
    }
  }
}

// ---------------- node GEMM: P[node][512] = emb @ [W1top | W1bot] ----------------
__global__ __launch_bounds__(256) void node_gemm(
    const unsigned short* __restrict__ emb_bf, const unsigned short* __restrict__ w1tn,
    unsigned short* __restrict__ P)
{
  __shared__ unsigned short As[64 * 72];   // 64 nodes x 64 k, +8 pad
  int t = threadIdx.x;
  int n0 = blockIdx.x * 64;
  {
    int nl = t >> 2, part = t & 3;
    int node = n0 + nl; if (node >= NNODES) node = 0;
    const int4* src = (const int4*)(emb_bf + node * 64 + part * 16);
    int4* dst = (int4*)(As + nl * 72 + part * 16);
    dst[0] = src[0]; dst[1] = src[1];
  }
  __syncthreads();
  int w = t >> 6, lane = t & 63, q = lane >> 4, c = lane & 15;
  f32x4 acc[4][8];
  for (int a = 0; a < 4; a++) for (int b = 0; b < 8; b++) for (int r = 0; r < 4; r++) acc[a][b][r] = 0.f;
  for (int k0 = 0; k0 < 64; k0 += 32){
    bf16x8 af[4];
    for (int tt = 0; tt < 4; tt++) af[tt] = *(const bf16x8*)(As + (tt * 16 + c) * 72 + k0 + q * 8);
    for (int n4 = 0; n4 < 8; n4++){
      bf16x8 bw = *(const bf16x8*)(w1tn + (w * 128 + n4 * 16 + c) * 64 + k0 + q * 8);
      for (int tt = 0; tt < 4; tt++)
        acc[tt][n4] = __builtin_amdgcn_mfma_f32_16x16x32_bf16(af[tt], bw, acc[tt][n4], 0, 0, 0);
    }
  }
  for (int tt = 0; tt < 4; tt++){
    for (int r = 0; r < 4; r++){
      int node = n0 + tt * 16 + q * 4 + r;
      if (node < NNODES){
        unsigned short* dst = P + (size_t)node * 512 + w * 128 + c;
        for (int n4 = 0; n4 < 8; n4++) dst[n4 * 16] = f2bf(acc[tt][n4][r]);
      }
    }
  }
}

// ---------------- K1: gather + segmented stats1 ----------------
__global__ __launch_bounds__(256) void k1_gather(
    const unsigned short* __restrict__ P, const int4* __restrict__ emeta,
    float* __restrict__ sum1, float* __restrict__ sqs1)
{
  int lane = threadIdx.x & 63;
  int wid = (blockIdx.x * 256 + threadIdx.x) >> 6;
  if (wid >= NTILES) return;
  int p0 = wid * 64;
  int4 me = emeta[p0 + lane];
  int c4 = lane * 4;
  int s0 = __shfl(me.z, 0);
  bool uni = (__ballot(me.z == s0) == ~0ull);
  float sm0 = 0.f, sm1 = 0.f, sm2 = 0.f, sm3 = 0.f;
  float q0 = 0.f, q1 = 0.f, q2 = 0.f, q3 = 0.f;
  if (uni){
    ushort4 a = *(const ushort4*)(P + (size_t)__shfl(me.x, 0) * 512 + c4);
    ushort4 b = *(const ushort4*)(P + (size_t)__shfl(me.y, 0) * 512 + 256 + c4);
    #pragma unroll 4
    for (int e = 0; e < 64; e++){
      ushort4 an = a, bn = b;
      if (e < 63){
        an = *(const ushort4*)(P + (size_t)__shfl(me.x, e + 1) * 512 + c4);
        bn = *(const ushort4*)(P + (size_t)__shfl(me.y, e + 1) * 512 + 256 + c4);
      }
      float x0 = bf2f(a.x) + bf2f(b.x);
      float x1 = bf2f(a.y) + bf2f(b.y);
      float x2v = bf2f(a.z) + bf2f(b.z);
      float x3 = bf2f(a.w) + bf2f(b.w);
      sm0 += x0; q0 += x0 * x0;
      sm1 += x1; q1 += x1 * x1;
      sm2 += x2v; q2 += x2v * x2v;
      sm3 += x3; q3 += x3 * x3;
      a = an; b = bn;
    }
    float* sp = sum1 + s0 * 256 + c4;
    float* qp = sqs1 + s0 * 256 + c4;
    atomicAdd(sp + 0, sm0); atomicAdd(sp + 1, sm1); atomicAdd(sp + 2, sm2); atomicAdd(sp + 3, sm3);
    atomicAdd(qp + 0, q0);  atomicAdd(qp + 1, q1);  atomicAdd(qp + 2, q2);  atomicAdd(qp + 3, q3);
  } else {
    int cur = s0;
    ushort4 a = *(const ushort4*)(P + (size_t)__shfl(me.x, 0) * 512 + c4);
    ushort4 b = *(const ushort4*)(P + (size_t)__shfl(me.y, 0) * 512 + 256 + c4);
    for (int e = 0; e < 64; e++){
      ushort4 an = a, bn = b;
      if (e < 63){
        an = *(const ushort4*)(P + (size_t)__shfl(me.x, e + 1) * 512 + c4);
        bn = *(const ushort4*)(P + (size_t)__shfl(me.y, e + 1) * 512 + 256 + c4);
      }
      int s = __shfl(me.z, e);
      if (s != cur){
        float* sp = sum1 + cur * 256 + c4;
        float* qp = sqs1 + cur * 256 + c4;
        atomicAdd(sp + 0, sm0); atomicAdd(sp + 1, sm1); atomicAdd(sp + 2, sm2); atomicAdd(sp + 3, sm3);
        atomicAdd(qp + 0, q0);  atomicAdd(qp + 1, q1);  atomicAdd(qp + 2, q2);  atomicAdd(qp + 3, q3);
        sm0 = sm1 = sm2 = sm3 = 0.f; q0 = q1 = q2 = q3 = 0.f;
        cur = s;
      }
      float x0 = bf2f(a.x) + bf2f(b.x);
      float x1 = bf2f(a.y) + bf2f(b.y);
      float x2v = bf2f(a.z) + bf2f(b.z);
      float x3 = bf2f(a.w) + bf2f(b.w);
      sm0 += x0; q0 += x0 * x0;
      sm1 += x1; q1 += x1 * x1;
      sm2 += x2v; q2 += x2v * x2v;
      sm3 += x3; q3 += x3 * x3;
      a = an; b = bn;
    }
    float* sp = sum1 + cur * 256 + c4;
    float* qp = sqs1 + cur * 256 + c4;
    atomicAdd(sp + 0, sm0); atomicAdd(sp + 1, sm1); atomicAdd(sp + 2, sm2); atomicAdd(sp + 3, sm3);
    atomicAdd(qp + 0, q0);  atomicAdd(qp + 1, q1);  atomicAdd(qp + 2, q2);  atomicAdd(qp + 3, q3);
  }
}

// ---------------- finalize: emit rstd and mean*rstd ----------------
__global__ void finalize1(const float* __restrict__ sum1, const float* __restrict__ sqs1,
                          const float* __restrict__ cnt1f, float* __restrict__ r1,
                          float* __restrict__ mr1){
  int i = blockIdx.x * 256 + threadIdx.x;   // 512*256
  int g = i >> 8;
  float cnt = cnt1f[g];
  float m = sum1[i] / cnt;
  float v = sqs1[i] / cnt - m * m;
  v = fmaxf(v, 0.f);
  float r = rsqrtf(v + 1e-5f);
  r1[i] = r;
  mr1[i] = m * r;
}

__global__ void finalize2(const float* __restrict__ sum2, const float* __restrict__ sqs2,
                          const float* __restrict__ cnt1f, float* __restrict__ r2,
                          float* __restrict__ mr2){
  int i = blockIdx.x * 256 + threadIdx.x;   // 512*64
  int g = i >> 6;
  float cnt = cnt1f[g];
  float m = sum2[i] / cnt;
  float v = sqs2[i] / cnt - m * m;
  v = fmaxf(v, 0.f);
  float r = rsqrtf(v + 1e-5f);
  r2[i] = r;
  mr2[i] = m * r;
}

// ---------------- K2: gather -> norm/relu -> GEMM2 + stats2 + x2T store ----------------
__global__ __launch_bounds__(256) void k2_fused(
    const unsigned short* __restrict__ P, const unsigned short* __restrict__ w2t,
    const int4* __restrict__ emeta,
    const float* __restrict__ r1, const float* __restrict__ mr1,
    float* __restrict__ sum2, float* __restrict__ sqs2,
    unsigned short* __restrict__ x2t)
{
  __shared__ unsigned short Y[64 * 264];   // y1 tile, [edge][256ch] +8 pad
  __shared__ int segl[64];
  __shared__ short rsegA[64];
  __shared__ unsigned char rloA[65];
  __shared__ int nrunS;
  int t = threadIdx.x;
  int p0 = blockIdx.x * 64;
  int w = t >> 6, lane = t & 63, q = lane >> 4, c = lane & 15;
  if (t < 64) segl[t] = emeta[p0 + t].z;
  if (w == 0){
    int sN = segl[lane];
    int nxt = (lane < 63) ? segl[lane + 1] : sN;
    unsigned long long mask = __ballot(sN != nxt);
    if (lane == 0){
      if (mask == 0ull){
        nrunS = 1; rloA[0] = 0; rloA[1] = 64; rsegA[0] = (short)sN;
      } else {
        int n = 0, cur = segl[0];
        rsegA[0] = (short)cur; rloA[0] = 0;
        for (int i = 1; i < 64; i++)
          if (segl[i] != cur){ cur = segl[i]; n++; rsegA[n] = (short)cur; rloA[n] = (unsigned char)i; }
        rloA[n + 1] = 64; nrunS = n + 1;
      }
    }
  }
  int c4 = lane * 4;
  int elb0 = w * 16;
  int4 me = emeta[p0 + elb0 + (lane & 15)];
  __syncthreads();
  int nrun = nrunS;
  bool uni = (nrun == 1);

  float4 r4, mr4;
  if (uni){
    int s0 = segl[0];
    r4  = *(const float4*)(r1  + s0 * 256 + c4);
    mr4 = *(const float4*)(mr1 + s0 * 256 + c4);
  }
  for (int e = 0; e < 16; e++){
    int ce = __shfl(me.x, e);
    int re = __shfl(me.y, e);
    if (!uni){
      int s = __shfl(me.z, e);
      r4  = *(const float4*)(r1  + s * 256 + c4);
      mr4 = *(const float4*)(mr1 + s * 256 + c4);
    }
    ushort4 a = *(const ushort4*)(P + (size_t)ce * 512 + c4);
    ushort4 b = *(const ushort4*)(P + (size_t)re * 512 + 256 + c4);
    float y0 = fmaxf(0.f, (bf2f(a.x) + bf2f(b.x)) * r4.x - mr4.x);
    float y1 = fmaxf(0.f, (bf2f(a.y) + bf2f(b.y)) * r4.y - mr4.y);
    float y2 = fmaxf(0.f, (bf2f(a.z) + bf2f(b.z)) * r4.z - mr4.z);
    float y3 = fmaxf(0.f, (bf2f(a.w) + bf2f(b.w)) * r4.w - mr4.w);
    uint2 pk;
    pk.x = pk2bf(y0, y1);
    pk.y = pk2bf(y2, y3);
    *(uint2*)(Y + (elb0 + e) * 264 + c4) = pk;
  }
  __syncthreads();

  // GEMM2: wave w owns out-channels [w*16, w*16+16)
  f32x4 acc2[4];
  for (int tt = 0; tt < 4; tt++) for (int r = 0; r < 4; r++) acc2[tt][r] = 0.f;
  int ch2 = w * 16 + c;
  for (int kc = 0; kc < 8; kc++){
    int k0 = kc * 32;
    bf16x8 bfr = *(const bf16x8*)(w2t + ch2 * 256 + k0 + q * 8);
    for (int tt = 0; tt < 4; tt++){
      bf16x8 afr = *(const bf16x8*)(Y + (tt * 16 + c) * 264 + k0 + q * 8);
      acc2[tt] = __builtin_amdgcn_mfma_f32_16x16x32_bf16(afr, bfr, acc2[tt], 0, 0, 0);
    }
  }

  if (uni){
    int s = segl[0];
    float sm = 0.f, sq = 0.f;
    for (int tt = 0; tt < 4; tt++)
      for (int r = 0; r < 4; r++){
        float v = acc2[tt][r];
        sm += v; sq += v * v;
      }
    sm += __shfl_xor(sm, 16); sq += __shfl_xor(sq, 16);
    sm += __shfl_xor(sm, 32); sq += __shfl_xor(sq, 32);
    if (q == 0){
      atomicAdd(&sum2[s * 64 + ch2], sm);
      atomicAdd(&sqs2[s * 64 + ch2], sq);
    }
  } else {
    for (int rr = 0; rr < nrun; rr++){
      int s = rsegA[rr], lo = rloA[rr], hi = rloA[rr + 1];
      float sm = 0.f, sq = 0.f;
      for (int tt = 0; tt < 4; tt++){
        int elb = tt * 16 + q * 4;
        for (int r = 0; r < 4; r++){
          int el = elb + r;
          if (el >= lo && el < hi){
            float v = acc2[tt][r];
            sm += v; sq += v * v;
          }
        }
      }
      sm += __shfl_xor(sm, 16); sq += __shfl_xor(sq, 16);
      sm += __shfl_xor(sm, 32); sq += __shfl_xor(sq, 32);
      if (q == 0){
        atomicAdd(&sum2[s * 64 + ch2], sm);
        atomicAdd(&sqs2[s * 64 + ch2], sq);
      }
    }
  }
  // x2T store: [ch][edge], ushort4 over 4 consecutive edges
  for (int tt = 0; tt < 4; tt++){
    uint2 pk;
    pk.x = pk2bf(acc2[tt][0], acc2[tt][1]);
    pk.y = pk2bf(acc2[tt][2], acc2[tt][3]);
    *(uint2*)(x2t + (size_t)ch2 * EDGES + p0 + tt * 16 + q * 4) = pk;
  }
}

// ---------------- K3: normalize2 + GEMV W3 (transposed x2) ----------------
__global__ __launch_bounds__(256) void k3_out(
    const unsigned short* __restrict__ x2t, const int4* __restrict__ emeta,
    const float* __restrict__ r2, const float* __restrict__ mr2,
    const float* __restrict__ W3, const float* __restrict__ b3, float* __restrict__ out)
{
  int pp = blockIdx.x * 256 + threadIdx.x;
  if (pp >= EDGES) return;
  int4 me = emeta[pp];
  const float* r2p  = r2  + me.z * 64;
  const float* mr2p = mr2 + me.z * 64;
  float acc = 0.f;
  #pragma unroll 8
  for (int ch = 0; ch < 64; ch++){
    float v = bf2f(x2t[(size_t)ch * EDGES + pp]);
    float y = fmaxf(0.f, v * r2p[ch] - mr2p[ch]);
    acc += y * W3[ch];
  }
  out[me.w] = acc + b3[0];
}

// ---------------- launch ----------------
extern "C" void kernel_launch(void* const* d_in, const int* in_sizes, int n_in,
                              void* d_out, int out_size, void* d_ws, size_t ws_size,
                              hipStream_t stream)
{
  (void)in_sizes; (void)n_in; (void)out_size;
  const float* emb = (const float*)d_in[0];
  const float* W1  = (const float*)d_in[1];
  const float* W2  = (const float*)d_in[3];
  const float* W3  = (const float*)d_in[5];
  const float* b3  = (const float*)d_in[6];
  const int* ei    = (const int*)d_in[7];
  const int* batch = (const int*)d_in[8];
  float* out = (float*)d_out;

  char* p = (char*)d_ws;
  size_t off = 0;
  auto take = [&](size_t n) -> char* {
    char* r = p + off;
    off += (n + 255) & ~(size_t)255;
    return r;
  };

  unsigned short* emb_bf = (unsigned short*)take((size_t)NNODES * 64 * 2);
  unsigned short* w1tn   = (unsigned short*)take(32768 * 2);
  unsigned short* w2t    = (unsigned short*)take(16384 * 2);
  int4* emeta = (int4*)take((size_t)EDGES * 16);
  unsigned short* P   = (unsigned short*)take((size_t)NNODES * 512 * 2);
  unsigned short* x2t = (unsigned short*)take((size_t)EDGES * 64 * 2);
  float* r1  = (float*)take(512 * 256 * 4);
  float* mr1 = (float*)take(512 * 256 * 4);
  float* r2  = (float*)take(512 * 64 * 4);
  float* mr2 = (float*)take(512 * 64 * 4);
  float* cnt1f = (float*)take(512 * 4);
  // zero-init region (contiguous)
  char* zbase = p + off;
  unsigned* hist    = (unsigned*)take(512 * 4);
  unsigned* cursors = (unsigned*)take(512 * 16 * 4);
  float* sum1 = (float*)take(512 * 256 * 4);
  float* sqs1 = (float*)take(512 * 256 * 4);
  float* sum2 = (float*)take(512 * 64 * 4);
  float* sqs2 = (float*)take(512 * 64 * 4);
  size_t zsize = (size_t)((p + off) - zbase);

  if (ws_size < off) return;  // workspace too small — fail loudly via poison

  hipMemsetAsync(zbase, 0, zsize, stream);
  prep_all<<<12692, 256, 0, stream>>>(emb, W1, W2, emb_bf, w1tn, w2t);
  seg_hist<<<977, 256, 0, stream>>>(ei, batch, hist);
  scan_hist<<<1, 512, 0, stream>>>(hist, cursors, cnt1f);
  scatter<<<977, 256, 0, stream>>>(ei, batch, cursors, emeta);
  node_gemm<<<(NNODES + 63) / 64, 256, 0, stream>>>(emb_bf, w1tn, P);
  k1_gather<<<(NTILES + 3) / 4, 256, 0, stream>>>(P, emeta, sum1, sqs1);
  finalize1<<<512, 256, 0, stream>>>(sum1, sqs1, cnt1f, r1, mr1);
  k2_fused<<<NTILES, 256, 0, stream>>>(P, w2t, emeta, r1, mr1, sum2, sqs2, x2t);
  finalize2<<<128, 256, 0, stream>>>(sum2, sqs2, cnt1f, r2, mr2);
  k3_out<<<3907, 256, 0, stream>>>(x2t, emeta, r2, mr2, W3, b3, out);
}

// Round 4
// 592.868 us; speedup vs baseline: 1.7046x; 1.1191x over previous
//
#include <hip/hip_runtime.h>
#include <hip/hip_bf16.h>

#define EDGES 1000000
#define NNODES 50000
#define NG 512
#define NTILES 15625  // EDGES/64
#define NCOLB 50176   // col-hist bins rounded to 196*256

typedef __attribute__((ext_vector_type(8))) short bf16x8;
typedef __attribute__((ext_vector_type(4))) float f32x4;

__device__ __forceinline__ unsigned short f2bf(float f){
  unsigned u = __float_as_uint(f);
  u += 0x7fffu + ((u >> 16) & 1u);
  return (unsigned short)(u >> 16);
}
__device__ __forceinline__ float bf2f(unsigned short h){
  return __uint_as_float(((unsigned)h) << 16);
}
__device__ __forceinline__ unsigned pk2bf(float x, float y){
  __hip_bfloat162 h = __float22bfloat162_rn(make_float2(x, y));
  union { __hip_bfloat162 h; unsigned u; } cv; cv.h = h;
  return cv.u;
}

// ---------------- prep: emb->bf16, W1->w1tn, W2->w2t ----------------
__global__ void prep_all(const float* __restrict__ emb, const float* __restrict__ W1,
                         const float* __restrict__ W2,
                         unsigned short* __restrict__ emb_bf,
                         unsigned short* __restrict__ w1tn, unsigned short* __restrict__ w2t){
  int i = blockIdx.x * 256 + threadIdx.x;
  if (i < NNODES * 64){
    emb_bf[i] = f2bf(emb[i]);
  } else {
    int j = i - NNODES * 64;
    if (j < 32768){
      int jj = j >> 6, k = j & 63;
      float v = (jj < 256) ? W1[k * 256 + jj] : W1[(k + 64) * 256 + (jj - 256)];
      w1tn[j] = f2bf(v);
    } else {
      int jj = j - 32768;
      if (jj < 16384){
        int n = jj >> 8, k = jj & 255;
        w2t[jj] = f2bf(W2[k * 64 + n]);
      }
    }
  }
}

// ---------------- per-graph edge counts (for mean denom) ----------------
__global__ void seg_hist(const int* __restrict__ ei, const int* __restrict__ batch,
                         unsigned* __restrict__ hist){
  __shared__ unsigned h[NG];
  int t = threadIdx.x;
  h[t] = 0; h[t + 256] = 0;
  __syncthreads();
  for (int i = 0; i < 4; i++){
    int e = blockIdx.x * 1024 + i * 256 + t;
    if (e < EDGES){
      int s = batch[ei[e]];
      atomicAdd(&h[s], 1u);
    }
  }
  __syncthreads();
  atomicAdd(&hist[t], h[t]);
  atomicAdd(&hist[t + 256], h[t + 256]);
}

// ---------------- counting sort by COL node (implies graph-sorted) ----------------
__global__ void col_hist(const int* __restrict__ ei, unsigned* __restrict__ chist){
  for (int i = 0; i < 4; i++){
    int e = blockIdx.x * 1024 + i * 256 + threadIdx.x;
    if (e < EDGES) atomicAdd(&chist[ei[e]], 1u);
  }
}

// block-local exclusive scan of 256-chunks + chunk sums
__global__ void col_scan1(const unsigned* __restrict__ chist, unsigned* __restrict__ cpre,
                          unsigned* __restrict__ bsum){
  __shared__ unsigned s[256];
  int t = threadIdx.x;
  int i = blockIdx.x * 256 + t;
  unsigned v = (i < NNODES) ? chist[i] : 0u;
  s[t] = v;
  __syncthreads();
  for (int o = 1; o < 256; o <<= 1){
    unsigned u = (t >= o) ? s[t - o] : 0u;
    __syncthreads();
    s[t] += u;
    __syncthreads();
  }
  cpre[i] = s[t] - v;                 // exclusive within block
  if (t == 255) bsum[blockIdx.x] = s[255];
}

__global__ void col_scan2(unsigned* __restrict__ bsum){   // 196 partials, 1 block
  __shared__ unsigned s[256];
  int t = threadIdx.x;
  unsigned v = (t < 196) ? bsum[t] : 0u;
  s[t] = v;
  __syncthreads();
  for (int o = 1; o < 256; o <<= 1){
    unsigned u = (t >= o) ? s[t - o] : 0u;
    __syncthreads();
    s[t] += u;
    __syncthreads();
  }
  if (t < 196) bsum[t] = s[t] - v;    // exclusive block offsets
}

__global__ void col_scan3(unsigned* __restrict__ cpre, const unsigned* __restrict__ bsum){
  int i = blockIdx.x * 256 + threadIdx.x;
  cpre[i] += bsum[blockIdx.x];
}

// emeta[pos] = (col, row, seg, orig_edge); cpre used as cursors (destructive)
__global__ void col_scatter(const int* __restrict__ ei, const int* __restrict__ batch,
                            unsigned* __restrict__ cpre, int4* __restrict__ emeta){
  for (int i = 0; i < 4; i++){
    int e = blockIdx.x * 1024 + i * 256 + threadIdx.x;
    if (e < EDGES){
      int cn = ei[e];
      int pos = (int)atomicAdd(&cpre[cn], 1u);
      emeta[pos] = make_int4(cn, ei[EDGES + e], batch[cn], e);
    }
  }
}

// ---------------- node GEMM: P[node][512] = emb @ [W1top | W1bot] ----------------
__global__ __launch_bounds__(256) void node_gemm(
    const unsigned short* __restrict__ emb_bf, const unsigned short* __restrict__ w1tn,
    unsigned short* __restrict__ P)
{
  __shared__ unsigned short As[64 * 72];   // 64 nodes x 64 k, +8 pad
  int t = threadIdx.x;
  int n0 = blockIdx.x * 64;
  {
    int nl = t >> 2, part = t & 3;
    int node = n0 + nl; if (node >= NNODES) node = 0;
    const int4* src = (const int4*)(emb_bf + node * 64 + part * 16);
    int4* dst = (int4*)(As + nl * 72 + part * 16);
    dst[0] = src[0]; dst[1] = src[1];
  }
  __syncthreads();
  int w = t >> 6, lane = t & 63, q = lane >> 4, c = lane & 15;
  f32x4 acc[4][8];
  for (int a = 0; a < 4; a++) for (int b = 0; b < 8; b++) for (int r = 0; r < 4; r++) acc[a][b][r] = 0.f;
  for (int k0 = 0; k0 < 64; k0 += 32){
    bf16x8 af[4];
    for (int tt = 0; tt < 4; tt++) af[tt] = *(const bf16x8*)(As + (tt * 16 + c) * 72 + k0 + q * 8);
    for (int n4 = 0; n4 < 8; n4++){
      bf16x8 bw = *(const bf16x8*)(w1tn + (w * 128 + n4 * 16 + c) * 64 + k0 + q * 8);
      for (int tt = 0; tt < 4; tt++)
        acc[tt][n4] = __builtin_amdgcn_mfma_f32_16x16x32_bf16(af[tt], bw, acc[tt][n4], 0, 0, 0);
    }
  }
  for (int tt = 0; tt < 4; tt++){
    for (int r = 0; r < 4; r++){
      int node = n0 + tt * 16 + q * 4 + r;
      if (node < NNODES){
        unsigned short* dst = P + (size_t)node * 512 + w * 128 + c;
        for (int n4 = 0; n4 < 8; n4++) dst[n4 * 16] = f2bf(acc[tt][n4][r]);
      }
    }
  }
}

// ---------------- K1: gather + segmented stats1 ----------------
__global__ __launch_bounds__(256) void k1_gather(
    const unsigned short* __restrict__ P, const int4* __restrict__ emeta,
    float* __restrict__ sum1, float* __restrict__ sqs1)
{
  int lane = threadIdx.x & 63;
  int wid = (blockIdx.x * 256 + threadIdx.x) >> 6;
  if (wid >= NTILES) return;
  int p0 = wid * 64;
  int4 me = emeta[p0 + lane];
  int c4 = lane * 4;
  int s0 = __builtin_amdgcn_readlane(me.z, 0);
  bool uni = (__ballot(me.z == s0) == ~0ull);
  float sm0 = 0.f, sm1 = 0.f, sm2 = 0.f, sm3 = 0.f;
  float q0 = 0.f, q1 = 0.f, q2 = 0.f, q3 = 0.f;
  if (uni){
    int cprev = -1;
    ushort4 a = make_ushort4(0,0,0,0);
    int re = __builtin_amdgcn_readlane(me.y, 0);
    ushort4 b = *(const ushort4*)(P + (size_t)re * 512 + 256 + c4);
    #pragma unroll 4
    for (int e = 0; e < 64; e++){
      ushort4 bn = b;
      if (e < 63){
        int rn = __builtin_amdgcn_readlane(me.y, e + 1);
        bn = *(const ushort4*)(P + (size_t)rn * 512 + 256 + c4);
      }
      int ce = __builtin_amdgcn_readlane(me.x, e);
      if (ce != cprev){ a = *(const ushort4*)(P + (size_t)ce * 512 + c4); cprev = ce; }
      float x0 = bf2f(a.x) + bf2f(b.x);
      float x1 = bf2f(a.y) + bf2f(b.y);
      float x2v = bf2f(a.z) + bf2f(b.z);
      float x3 = bf2f(a.w) + bf2f(b.w);
      sm0 += x0; q0 += x0 * x0;
      sm1 += x1; q1 += x1 * x1;
      sm2 += x2v; q2 += x2v * x2v;
      sm3 += x3; q3 += x3 * x3;
      b = bn;
    }
    float* sp = sum1 + s0 * 256 + c4;
    float* qp = sqs1 + s0 * 256 + c4;
    atomicAdd(sp + 0, sm0); atomicAdd(sp + 1, sm1); atomicAdd(sp + 2, sm2); atomicAdd(sp + 3, sm3);
    atomicAdd(qp + 0, q0);  atomicAdd(qp + 1, q1);  atomicAdd(qp + 2, q2);  atomicAdd(qp + 3, q3);
  } else {
    int cur = s0;
    int cprev = -1;
    ushort4 a = make_ushort4(0,0,0,0);
    for (int e = 0; e < 64; e++){
      int ce = __builtin_amdgcn_readlane(me.x, e);
      int re = __builtin_amdgcn_readlane(me.y, e);
      if (ce != cprev){ a = *(const ushort4*)(P + (size_t)ce * 512 + c4); cprev = ce; }
      ushort4 b = *(const ushort4*)(P + (size_t)re * 512 + 256 + c4);
      int s = __builtin_amdgcn_readlane(me.z, e);
      if (s != cur){
        float* sp = sum1 + cur * 256 + c4;
        float* qp = sqs1 + cur * 256 + c4;
        atomicAdd(sp + 0, sm0); atomicAdd(sp + 1, sm1); atomicAdd(sp + 2, sm2); atomicAdd(sp + 3, sm3);
        atomicAdd(qp + 0, q0);  atomicAdd(qp + 1, q1);  atomicAdd(qp + 2, q2);  atomicAdd(qp + 3, q3);
        sm0 = sm1 = sm2 = sm3 = 0.f; q0 = q1 = q2 = q3 = 0.f;
        cur = s;
      }
      float x0 = bf2f(a.x) + bf2f(b.x);
      float x1 = bf2f(a.y) + bf2f(b.y);
      float x2v = bf2f(a.z) + bf2f(b.z);
      float x3 = bf2f(a.w) + bf2f(b.w);
      sm0 += x0; q0 += x0 * x0;
      sm1 += x1; q1 += x1 * x1;
      sm2 += x2v; q2 += x2v * x2v;
      sm3 += x3; q3 += x3 * x3;
    }
    float* sp = sum1 + cur * 256 + c4;
    float* qp = sqs1 + cur * 256 + c4;
    atomicAdd(sp + 0, sm0); atomicAdd(sp + 1, sm1); atomicAdd(sp + 2, sm2); atomicAdd(sp + 3, sm3);
    atomicAdd(qp + 0, q0);  atomicAdd(qp + 1, q1);  atomicAdd(qp + 2, q2);  atomicAdd(qp + 3, q3);
  }
}

// ---------------- finalize: emit rstd and mean*rstd ----------------
__global__ void finalize1(const float* __restrict__ sum1, const float* __restrict__ sqs1,
                          const unsigned* __restrict__ hist, float* __restrict__ r1,
                          float* __restrict__ mr1){
  int i = blockIdx.x * 256 + threadIdx.x;   // 512*256
  int g = i >> 8;
  float cnt = fmaxf((float)hist[g], 1.f);
  float m = sum1[i] / cnt;
  float v = sqs1[i] / cnt - m * m;
  v = fmaxf(v, 0.f);
  float r = rsqrtf(v + 1e-5f);
  r1[i] = r;
  mr1[i] = m * r;
}

__global__ void finalize2(const float* __restrict__ sum2, const float* __restrict__ sqs2,
                          const unsigned* __restrict__ hist, float* __restrict__ r2,
                          float* __restrict__ mr2){
  int i = blockIdx.x * 256 + threadIdx.x;   // 512*64
  int g = i >> 6;
  float cnt = fmaxf((float)hist[g], 1.f);
  float m = sum2[i] / cnt;
  float v = sqs2[i] / cnt - m * m;
  v = fmaxf(v, 0.f);
  float r = rsqrtf(v + 1e-5f);
  r2[i] = r;
  mr2[i] = m * r;
}

// ---------------- K2: gather -> norm/relu -> GEMM2 + stats2 + x2T store ----------------
__global__ __launch_bounds__(256) void k2_fused(
    const unsigned short* __restrict__ P, const unsigned short* __restrict__ w2t,
    const int4* __restrict__ emeta,
    const float* __restrict__ r1, const float* __restrict__ mr1,
    float* __restrict__ sum2, float* __restrict__ sqs2,
    unsigned short* __restrict__ x2t)
{
  __shared__ unsigned short Y[64 * 264];   // y1 tile, [edge][256ch] +8 pad
  __shared__ int segl[64];
  __shared__ short rsegA[64];
  __shared__ unsigned char rloA[65];
  __shared__ int nrunS;
  int t = threadIdx.x;
  int p0 = blockIdx.x * 64;
  int w = t >> 6, lane = t & 63, q = lane >> 4, c = lane & 15;
  if (t < 64) segl[t] = emeta[p0 + t].z;
  if (w == 0){
    int sN = segl[lane];
    int nxt = (lane < 63) ? segl[lane + 1] : sN;
    unsigned long long mask = __ballot(sN != nxt);
    if (lane == 0){
      if (mask == 0ull){
        nrunS = 1; rloA[0] = 0; rloA[1] = 64; rsegA[0] = (short)sN;
      } else {
        int n = 0, cur = segl[0];
        rsegA[0] = (short)cur; rloA[0] = 0;
        for (int i = 1; i < 64; i++)
          if (segl[i] != cur){ cur = segl[i]; n++; rsegA[n] = (short)cur; rloA[n] = (unsigned char)i; }
        rloA[n + 1] = 64; nrunS = n + 1;
      }
    }
  }
  int c4 = lane * 4;
  int elb0 = w * 16;
  int4 me = emeta[p0 + elb0 + (lane & 15)];
  __syncthreads();
  int nrun = nrunS;
  bool uni = (nrun == 1);

  float4 r4, mr4;
  if (uni){
    int s0 = segl[0];
    r4  = *(const float4*)(r1  + s0 * 256 + c4);
    mr4 = *(const float4*)(mr1 + s0 * 256 + c4);
  }
  {
    int cprev = -1;
    ushort4 a = make_ushort4(0,0,0,0);
    int re = __builtin_amdgcn_readlane(me.y, 0);
    ushort4 b = *(const ushort4*)(P + (size_t)re * 512 + 256 + c4);
    for (int e = 0; e < 16; e++){
      ushort4 bn = b;
      if (e < 15){
        int rn = __builtin_amdgcn_readlane(me.y, e + 1);
        bn = *(const ushort4*)(P + (size_t)rn * 512 + 256 + c4);
      }
      int ce = __builtin_amdgcn_readlane(me.x, e);
      if (ce != cprev){ a = *(const ushort4*)(P + (size_t)ce * 512 + c4); cprev = ce; }
      if (!uni){
        int s = __builtin_amdgcn_readlane(me.z, e);
        r4  = *(const float4*)(r1  + s * 256 + c4);
        mr4 = *(const float4*)(mr1 + s * 256 + c4);
      }
      float y0 = fmaxf(0.f, (bf2f(a.x) + bf2f(b.x)) * r4.x - mr4.x);
      float y1 = fmaxf(0.f, (bf2f(a.y) + bf2f(b.y)) * r4.y - mr4.y);
      float y2 = fmaxf(0.f, (bf2f(a.z) + bf2f(b.z)) * r4.z - mr4.z);
      float y3 = fmaxf(0.f, (bf2f(a.w) + bf2f(b.w)) * r4.w - mr4.w);
      uint2 pk;
      pk.x = pk2bf(y0, y1);
      pk.y = pk2bf(y2, y3);
      *(uint2*)(Y + (elb0 + e) * 264 + c4) = pk;
      b = bn;
    }
  }
  __syncthreads();

  // GEMM2: wave w owns out-channels [w*16, w*16+16)
  f32x4 acc2[4];
  for (int tt = 0; tt < 4; tt++) for (int r = 0; r < 4; r++) acc2[tt][r] = 0.f;
  int ch2 = w * 16 + c;
  for (int kc = 0; kc < 8; kc++){
    int k0 = kc * 32;
    bf16x8 bfr = *(const bf16x8*)(w2t + ch2 * 256 + k0 + q * 8);
    for (int tt = 0; tt < 4; tt++){
      bf16x8 afr = *(const bf16x8*)(Y + (tt * 16 + c) * 264 + k0 + q * 8);
      acc2[tt] = __builtin_amdgcn_mfma_f32_16x16x32_bf16(afr, bfr, acc2[tt], 0, 0, 0);
    }
  }

  if (uni){
    int s = segl[0];
    float sm = 0.f, sq = 0.f;
    for (int tt = 0; tt < 4; tt++)
      for (int r = 0; r < 4; r++){
        float v = acc2[tt][r];
        sm += v; sq += v * v;
      }
    sm += __shfl_xor(sm, 16); sq += __shfl_xor(sq, 16);
    sm += __shfl_xor(sm, 32); sq += __shfl_xor(sq, 32);
    if (q == 0){
      atomicAdd(&sum2[s * 64 + ch2], sm);
      atomicAdd(&sqs2[s * 64 + ch2], sq);
    }
  } else {
    for (int rr = 0; rr < nrun; rr++){
      int s = rsegA[rr], lo = rloA[rr], hi = rloA[rr + 1];
      float sm = 0.f, sq = 0.f;
      for (int tt = 0; tt < 4; tt++){
        int elb = tt * 16 + q * 4;
        for (int r = 0; r < 4; r++){
          int el = elb + r;
          if (el >= lo && el < hi){
            float v = acc2[tt][r];
            sm += v; sq += v * v;
          }
        }
      }
      sm += __shfl_xor(sm, 16); sq += __shfl_xor(sq, 16);
      sm += __shfl_xor(sm, 32); sq += __shfl_xor(sq, 32);
      if (q == 0){
        atomicAdd(&sum2[s * 64 + ch2], sm);
        atomicAdd(&sqs2[s * 64 + ch2], sq);
      }
    }
  }
  // x2T store: [ch][edge], ushort4 over 4 consecutive edges
  for (int tt = 0; tt < 4; tt++){
    uint2 pk;
    pk.x = pk2bf(acc2[tt][0], acc2[tt][1]);
    pk.y = pk2bf(acc2[tt][2], acc2[tt][3]);
    *(uint2*)(x2t + (size_t)ch2 * EDGES + p0 + tt * 16 + q * 4) = pk;
  }
}

// ---------------- K3: normalize2 + GEMV W3 (transposed x2) ----------------
__global__ __launch_bounds__(256) void k3_out(
    const unsigned short* __restrict__ x2t, const int4* __restrict__ emeta,
    const float* __restrict__ r2, const float* __restrict__ mr2,
    const float* __restrict__ W3, const float* __restrict__ b3, float* __restrict__ out)
{
  int pp = blockIdx.x * 256 + threadIdx.x;
  if (pp >= EDGES) return;
  int4 me = emeta[pp];
  const float* r2p  = r2  + me.z * 64;
  const float* mr2p = mr2 + me.z * 64;
  float acc = 0.f;
  #pragma unroll 8
  for (int ch = 0; ch < 64; ch++){
    float v = bf2f(x2t[(size_t)ch * EDGES + pp]);
    float y = fmaxf(0.f, v * r2p[ch] - mr2p[ch]);
    acc += y * W3[ch];
  }
  out[me.w] = acc + b3[0];
}

// ---------------- launch ----------------
extern "C" void kernel_launch(void* const* d_in, const int* in_sizes, int n_in,
                              void* d_out, int out_size, void* d_ws, size_t ws_size,
                              hipStream_t stream)
{
  (void)in_sizes; (void)n_in; (void)out_size;
  const float* emb = (const float*)d_in[0];
  const float* W1  = (const float*)d_in[1];
  const float* W2  = (const float*)d_in[3];
  const float* W3  = (const float*)d_in[5];
  const float* b3  = (const float*)d_in[6];
  const int* ei    = (const int*)d_in[7];
  const int* batch = (const int*)d_in[8];
  float* out = (float*)d_out;

  char* p = (char*)d_ws;
  size_t off = 0;
  auto take = [&](size_t n) -> char* {
    char* r = p + off;
    off += (n + 255) & ~(size_t)255;
    return r;
  };

  unsigned short* emb_bf = (unsigned short*)take((size_t)NNODES * 64 * 2);
  unsigned short* w1tn   = (unsigned short*)take(32768 * 2);
  unsigned short* w2t    = (unsigned short*)take(16384 * 2);
  int4* emeta = (int4*)take((size_t)EDGES * 16);
  unsigned short* P   = (unsigned short*)take((size_t)NNODES * 512 * 2);
  unsigned short* x2t = (unsigned short*)take((size_t)EDGES * 64 * 2);
  float* r1  = (float*)take(512 * 256 * 4);
  float* mr1 = (float*)take(512 * 256 * 4);
  float* r2  = (float*)take(512 * 64 * 4);
  float* mr2 = (float*)take(512 * 64 * 4);
  unsigned* cpre = (unsigned*)take(NCOLB * 4);
  unsigned* bsum = (unsigned*)take(256 * 4);
  // zero-init region (contiguous)
  char* zbase = p + off;
  unsigned* hist  = (unsigned*)take(NG * 4);
  unsigned* chist = (unsigned*)take(NCOLB * 4);
  float* sum1 = (float*)take(512 * 256 * 4);
  float* sqs1 = (float*)take(512 * 256 * 4);
  float* sum2 = (float*)take(512 * 64 * 4);
  float* sqs2 = (float*)take(512 * 64 * 4);
  size_t zsize = (size_t)((p + off) - zbase);

  if (ws_size < off) return;  // workspace too small — fail loudly via poison

  hipMemsetAsync(zbase, 0, zsize, stream);
  prep_all<<<12692, 256, 0, stream>>>(emb, W1, W2, emb_bf, w1tn, w2t);
  seg_hist<<<977, 256, 0, stream>>>(ei, batch, hist);
  col_hist<<<977, 256, 0, stream>>>(ei, chist);
  col_scan1<<<196, 256, 0, stream>>>(chist, cpre, bsum);
  col_scan2<<<1, 256, 0, stream>>>(bsum);
  col_scan3<<<196, 256, 0, stream>>>(cpre, bsum);
  col_scatter<<<977, 256, 0, stream>>>(ei, batch, cpre, emeta);
  node_gemm<<<(NNODES + 63) / 64, 256, 0, stream>>>(emb_bf, w1tn, P);
  k1_gather<<<(NTILES + 3) / 4, 256, 0, stream>>>(P, emeta, sum1, sqs1);
  finalize1<<<512, 256, 0, stream>>>(sum1, sqs1, hist, r1, mr1);
  k2_fused<<<NTILES, 256, 0, stream>>>(P, w2t, emeta, r1, mr1, sum2, sqs2, x2t);
  finalize2<<<128, 256, 0, stream>>>(sum2, sqs2, hist, r2, mr2);
  k3_out<<<3907, 256, 0, stream>>>(x2t, emeta, r2, mr2, W3, b3, out);
}